// Round 10
// baseline (159.179 us; speedup 1.0000x reference)
//
#include <hip/hip_runtime.h>

// Problem constants (match setup_inputs)
#define BB     4
#define NN     8192
#define DD     128
#define KNN    32
#define BN     (BB*NN)        // 32768 rows total
#define NK     (NN*KNN)       // 262144 edges per batch (2^18)
#define RPB    64             // destination ranges per batch
#define RROWS  128            // rows per range
#define RCAP   4608           // slots per range (mean 4096, +8 sigma)
#define NRANGE (BB*RPB)       // 256 ranges total
#define SCAP   4608           // staging slots per range
#define BCAP   48             // phase-A bucket cap (mean 16, +8 sigma)

static __device__ __forceinline__ float inv_denom() { return 1.0f / 32.000001f; }

// ---------------------------------------------------------------------------
// Bmat[e*256 + j]:
//   j <  128 (c=j):     M[c,e] = sum_d Wq[c,d]*Wk[e,d]
//   j >= 128 (o=j-128): P[e,o] = sum_d Wv[e,d]*Wout[d,o]
// Block 0 also zeroes gcursor (stream-ordered before partition_kernel),
// replacing a hipMemsetAsync that measured ~42 us/call in-stream.
// ---------------------------------------------------------------------------
__global__ void compute_bmat(const float* __restrict__ Wqkv,
                             const float* __restrict__ Wout,
                             float* __restrict__ Bmat,
                             int* __restrict__ gcursor) {
    int e = blockIdx.x;      // 0..127
    int j = threadIdx.x;     // 0..255
    if (e == 0) gcursor[j] = 0;          // NRANGE == 256 == blockDim
    float acc = 0.f;
    if (j < DD) {
        int c = j;
        #pragma unroll 4
        for (int d = 0; d < DD; ++d)
            acc += Wqkv[c*3*DD + d] * Wqkv[e*3*DD + DD + d];
    } else {
        int o = j - DD;
        #pragma unroll 4
        for (int d = 0; d < DD; ++d)
            acc += Wqkv[e*3*DD + 2*DD + d] * Wout[d*DD + o];
    }
    Bmat[e*2*DD + j] = acc;
}

// ---------------------------------------------------------------------------
// Phase A: radix partition. 1024 blocks x 256 threads; block = (batch, chunk
// of 1024 edges). Each edge scanned ONCE across the whole grid. Bin into 64
// range-buckets in LDS, reserve global space per bucket (one atomicAdd), and
// flush buckets as contiguous runs into staging[(batch*64+r)*SCAP ...].
// Payload: (m_local<<13) | nrow  (m_local = m&127, nrow = source row).
// ---------------------------------------------------------------------------
__global__ __launch_bounds__(256) void partition_kernel(
        const int* __restrict__ idx,
        int* __restrict__ staging,
        int* __restrict__ gcursor) {
    __shared__ int bucket[RPB][BCAP];
    __shared__ int bcnt[RPB];
    __shared__ int gbase[RPB];

    int t  = threadIdx.x;
    int bb = blockIdx.x;
    int batch = bb >> 8;                 // 256 chunks per batch
    int c = bb & 255;
    if (t < RPB) bcnt[t] = 0;
    __syncthreads();

    int4 v = reinterpret_cast<const int4*>(idx)[batch*(NK/4) + c*256 + t];
    int nrow = (c*256 + t) >> 3;         // 8 int4 (32 edges) per source row
    int mm[4] = {v.x, v.y, v.z, v.w};
    #pragma unroll
    for (int j = 0; j < 4; ++j) {
        int m = mm[j];
        int r = m >> 7;
        int p = atomicAdd(&bcnt[r], 1);
        if (p < BCAP) bucket[r][p] = ((m & 127) << 13) | nrow;
    }
    __syncthreads();

    if (t < RPB) {
        int n = min(bcnt[t], BCAP);
        bcnt[t] = n;
        gbase[t] = atomicAdd(&gcursor[batch*RPB + t], n);
    }
    __syncthreads();

    // flush: 64 buckets x 48 slots, coalesced 192 B runs
    for (int u = t; u < RPB*BCAP; u += 256) {
        int k = u / BCAP, s = u % BCAP;
        if (s < bcnt[k])
            staging[(size_t)(batch*RPB + k)*SCAP + gbase[k] + s] = bucket[k][s];
    }
}

// ---------------------------------------------------------------------------
// Phase B: per-range binning. 256 blocks x 512 threads; block owns one
// (batch, range) staging region (~4096 contiguous ints). Histogram by dest
// row -> wave-0 shuffle prefix scan -> LDS scatter -> coalesced u16 writes
// + per-row offsets/counts.
// ---------------------------------------------------------------------------
__global__ __launch_bounds__(512) void bin_kernel(
        const int* __restrict__ staging,
        const int* __restrict__ gcursor,
        unsigned short* __restrict__ srcs16,
        int* __restrict__ offsets,
        int* __restrict__ counts) {
    __shared__ unsigned short binned[RCAP];
    __shared__ int hist[RROWS], pfx[RROWS], cur[RROWS];

    int t  = threadIdx.x;
    int rg = blockIdx.x;                 // batch*64 + r
    int cnt = gcursor[rg];
    if (cnt > SCAP) cnt = SCAP;
    const int* sp = staging + (size_t)rg*SCAP;

    if (t < RROWS) { hist[t] = 0; cur[t] = 0; }
    __syncthreads();

    for (int u = t; u < cnt; u += 512)
        atomicAdd(&hist[sp[u] >> 13], 1);
    __syncthreads();

    // wave-0 shuffle prefix scan over 128 bins (2 bins/lane)
    if (t < 64) {
        int a = hist[2*t], b = hist[2*t+1];
        int s = a + b;
        #pragma unroll
        for (int d = 1; d < 64; d <<= 1) {
            int v = __shfl_up(s, d, 64);
            if (t >= d) s += v;
        }
        int excl = s - (a + b);
        pfx[2*t]   = excl;
        pfx[2*t+1] = excl + a;
    }
    __syncthreads();

    for (int u = t; u < cnt; u += 512) {
        int e = sp[u];
        int ml = e >> 13;
        int p = atomicAdd(&cur[ml], 1);
        binned[pfx[ml] + p] = (unsigned short)(e & 8191);
    }
    __syncthreads();

    int base = rg * RCAP;
    for (int u = t; u < cnt; u += 512) srcs16[base + u] = binned[u];
    if (t < RROWS) {
        int grow = (rg >> 6)*NN + (rg & 63)*RROWS + t;
        offsets[grow] = base + pfx[t];
        counts[grow]  = hist[t];
    }
}

// ---------------------------------------------------------------------------
// One diffusion hop, gather form, column-split (xcd = (batch<<1)|colhalf so
// each XCD's hot feature set is 2 MB, L2-resident). Per wave: one dest row;
// 4 streams x 16 lanes; 8 STATIC gather slots per lane issued back-to-back
// (128 B in flight) with mask-accumulate; rare tail loop for cnt>32.
// ---------------------------------------------------------------------------
__global__ __launch_bounds__(256) void hop_kernel(
        const float* __restrict__ fin, float* __restrict__ fout,
        const int* __restrict__ offsets, const int* __restrict__ counts,
        const unsigned short* __restrict__ srcs16) {
    int i = blockIdx.x;                 // 0..16383
    int xcd = i & 7;
    int batch = xcd >> 1, ch = xcd & 1;
    int j = i >> 3;                     // 0..2047
    int wave = threadIdx.x >> 6;
    int lane = threadIdx.x & 63;
    int h = lane >> 4;                  // stream 0..3
    int l16 = lane & 15;
    int g = batch*NN + j*4 + wave;      // global dest row

    int off = offsets[g];
    int cnt = counts[g];
    const unsigned short* sp = srcs16 + off;
    const float* fbatch = fin + (size_t)batch*NN*DD;
    int laneoff = ch*64 + l16*4;

    // load 8 slot ids (beyond-cnt slots are stale garbage; clamp, mask later)
    int ss[8];
    #pragma unroll
    for (int u = 0; u < 8; ++u) {
        int s = sp[h + 4*u];
        ss[u] = (s > NN-1) ? 0 : s;
    }
    // issue 8 independent gathers
    float4 vv[8];
    #pragma unroll
    for (int u = 0; u < 8; ++u)
        vv[u] = *reinterpret_cast<const float4*>(fbatch + ss[u]*DD + laneoff);
    // mask-accumulate
    float4 acc = make_float4(0.f, 0.f, 0.f, 0.f);
    #pragma unroll
    for (int u = 0; u < 8; ++u) {
        float mwt = (h + 4*u < cnt) ? 1.f : 0.f;
        acc.x += vv[u].x * mwt; acc.y += vv[u].y * mwt;
        acc.z += vv[u].z * mwt; acc.w += vv[u].w * mwt;
    }
    // tail (cnt > 32, ~45% of rows, avg ~3 extra edges)
    for (int e = 32 + h; e < cnt; e += 4) {
        int s = sp[e];
        float4 v = *reinterpret_cast<const float4*>(fbatch + s*DD + laneoff);
        acc.x += v.x; acc.y += v.y; acc.z += v.z; acc.w += v.w;
    }

    // combine 4 streams
    acc.x += __shfl_xor(acc.x, 16); acc.y += __shfl_xor(acc.y, 16);
    acc.z += __shfl_xor(acc.z, 16); acc.w += __shfl_xor(acc.w, 16);
    acc.x += __shfl_xor(acc.x, 32); acc.y += __shfl_xor(acc.y, 32);
    acc.z += __shfl_xor(acc.z, 32); acc.w += __shfl_xor(acc.w, 32);

    if (h == 0) {
        const float s = inv_denom();
        float4 o = make_float4(acc.x*s, acc.y*s, acc.z*s, acc.w*s);
        *reinterpret_cast<float4*>(fout + (size_t)g*DD + laneoff) = o;
    }
}

// ---------------------------------------------------------------------------
// Fused final stage: Y = X3 @ Bmat ([32768x128]@[128x256]),
//   attn[m] = x[m] . Y[m,0:128];  out[m,:] = attn[m]*Y[m,128:256] + b_out
// 32-row tiles -> 1024 blocks (4 blocks/CU, 4 waves/SIMD) for latency hiding;
// per-thread acc 4x8. Bmat stays global: active 4 KB k-slice x 4 blocks fits
// the 32 KB L1, so the 8x intra-block reuse is L1-served.
// ---------------------------------------------------------------------------
__global__ __launch_bounds__(256) void final_kernel(
        const float* __restrict__ x3, const float* __restrict__ x,
        const float* __restrict__ Bmat, const float* __restrict__ bout,
        float* __restrict__ out) {
    __shared__ float a_lds[32][DD];
    __shared__ float attn_lds[32];
    int t = threadIdx.x;
    int tc = t & 31, tr = t >> 5;       // tc: 8 cols each of 256; tr: 4 rows each of 32
    int row0 = blockIdx.x * 32;

    for (int u = t; u < 32*32; u += 256) {
        int r = u >> 5, cp = u & 31;
        *reinterpret_cast<float4*>(&a_lds[r][cp*4]) =
            *reinterpret_cast<const float4*>(x3 + (size_t)(row0 + r)*DD + cp*4);
    }
    if (t < 32) attn_lds[t] = 0.f;
    __syncthreads();

    float acc[4][8];
    #pragma unroll
    for (int r = 0; r < 4; ++r)
        #pragma unroll
        for (int u = 0; u < 8; ++u) acc[r][u] = 0.f;

    for (int k0 = 0; k0 < DD; k0 += 4) {
        float4 av[4];
        #pragma unroll
        for (int r = 0; r < 4; ++r)
            av[r] = *reinterpret_cast<const float4*>(&a_lds[tr*4 + r][k0]);
        #pragma unroll
        for (int kk = 0; kk < 4; ++kk) {
            float4 b0 = *reinterpret_cast<const float4*>(Bmat + (k0+kk)*256 + tc*8);
            float4 b1 = *reinterpret_cast<const float4*>(Bmat + (k0+kk)*256 + tc*8 + 4);
            #pragma unroll
            for (int r = 0; r < 4; ++r) {
                float a = (kk == 0) ? av[r].x : (kk == 1) ? av[r].y
                        : (kk == 2) ? av[r].z : av[r].w;
                acc[r][0] += a*b0.x; acc[r][1] += a*b0.y;
                acc[r][2] += a*b0.z; acc[r][3] += a*b0.w;
                acc[r][4] += a*b1.x; acc[r][5] += a*b1.y;
                acc[r][6] += a*b1.z; acc[r][7] += a*b1.w;
            }
        }
    }

    if (tc < 16) {
        #pragma unroll
        for (int r = 0; r < 4; ++r) {
            int row = row0 + tr*4 + r;
            const float4 xa = *reinterpret_cast<const float4*>(x + (size_t)row*DD + tc*8);
            const float4 xb = *reinterpret_cast<const float4*>(x + (size_t)row*DD + tc*8 + 4);
            float p = xa.x*acc[r][0] + xa.y*acc[r][1] + xa.z*acc[r][2] + xa.w*acc[r][3]
                    + xb.x*acc[r][4] + xb.y*acc[r][5] + xb.z*acc[r][6] + xb.w*acc[r][7];
            atomicAdd(&attn_lds[tr*4 + r], p);
        }
    }
    __syncthreads();

    if (tc >= 16) {
        int c0 = (tc - 16) * 8;
        float4 ba  = *reinterpret_cast<const float4*>(bout + c0);
        float4 bbv = *reinterpret_cast<const float4*>(bout + c0 + 4);
        #pragma unroll
        for (int r = 0; r < 4; ++r) {
            int row = row0 + tr*4 + r;
            float at = attn_lds[tr*4 + r];
            float4 o0, o1;
            o0.x = at*acc[r][0] + ba.x;  o0.y = at*acc[r][1] + ba.y;
            o0.z = at*acc[r][2] + ba.z;  o0.w = at*acc[r][3] + ba.w;
            o1.x = at*acc[r][4] + bbv.x; o1.y = at*acc[r][5] + bbv.y;
            o1.z = at*acc[r][6] + bbv.z; o1.w = at*acc[r][7] + bbv.w;
            *reinterpret_cast<float4*>(out + (size_t)row*DD + c0)     = o0;
            *reinterpret_cast<float4*>(out + (size_t)row*DD + c0 + 4) = o1;
        }
    }
}

// ---------------------------------------------------------------------------
// ws layout (~24.3 MB; measured ws_size ~268 MB):
//   f_a     @ 0         16777216 B   (x3 ping buffer)
//   srcs16  @ 16777216   2359552 B   (256*4608 u16 + pad)
//   offsets @ 19136768    131072 B
//   counts  @ 19267840    131072 B
//   Bmat    @ 19398912    131072 B
//   staging @ 19529984   4718592 B   (256*4608 int)
//   gcursor @ 24248576      1024 B
// ---------------------------------------------------------------------------
extern "C" void kernel_launch(void* const* d_in, const int* in_sizes, int n_in,
                              void* d_out, int out_size, void* d_ws, size_t ws_size,
                              hipStream_t stream) {
    const float* x    = (const float*)d_in[0];
    const int*   idx  = (const int*)  d_in[1];
    const float* Wqkv = (const float*)d_in[2];
    const float* Wout = (const float*)d_in[3];
    const float* bout = (const float*)d_in[4];
    float* out = (float*)d_out;

    char* ws = (char*)d_ws;
    float*          f_a     = (float*)(ws);
    unsigned short* srcs16  = (unsigned short*)(ws + 16777216);
    int*            offsets = (int*)(ws + 19136768);
    int*            counts  = (int*)(ws + 19267840);
    float*          Bmat    = (float*)(ws + 19398912);
    int*            staging = (int*)(ws + 19529984);
    int*            gcursor = (int*)(ws + 24248576);

    compute_bmat<<<DD, 256, 0, stream>>>(Wqkv, Wout, Bmat, gcursor);
    partition_kernel<<<1024, 256, 0, stream>>>(idx, staging, gcursor);
    bin_kernel<<<NRANGE, 512, 0, stream>>>(staging, gcursor, srcs16, offsets, counts);

    hop_kernel<<<16384, 256, 0, stream>>>(x,   f_a, offsets, counts, srcs16);
    hop_kernel<<<16384, 256, 0, stream>>>(f_a, out, offsets, counts, srcs16);
    hop_kernel<<<16384, 256, 0, stream>>>(out, f_a, offsets, counts, srcs16);

    final_kernel<<<BN/32, 256, 0, stream>>>(f_a, x, Bmat, bout, out);
}

// Round 11
// 152.041 us; speedup vs baseline: 1.0469x; 1.0469x over previous
//
#include <hip/hip_runtime.h>

// Problem constants (match setup_inputs)
#define BB     4
#define NN     8192
#define DD     128
#define KNN    32
#define BN     (BB*NN)        // 32768 rows total
#define NK     (NN*KNN)       // 262144 edges per batch (2^18)
#define RPB    64             // destination ranges per batch
#define RROWS  128            // rows per range
#define RCAP   4608           // slots per range (mean 4096, +8 sigma)
#define NRANGE (BB*RPB)       // 256 ranges total
#define SCAP   4608           // staging slots per range
#define BCAP   48             // phase-A bucket cap (mean 16, +8 sigma)

static __device__ __forceinline__ float inv_denom() { return 1.0f / 32.000001f; }

// ---------------------------------------------------------------------------
// Bmat[e*256 + j]:
//   j <  128 (c=j):     M[c,e] = sum_d Wq[c,d]*Wk[e,d]
//   j >= 128 (o=j-128): P[e,o] = sum_d Wv[e,d]*Wout[d,o]
// Block 0 also zeroes gcursor (stream-ordered before partition_kernel).
// ---------------------------------------------------------------------------
__global__ void compute_bmat(const float* __restrict__ Wqkv,
                             const float* __restrict__ Wout,
                             float* __restrict__ Bmat,
                             int* __restrict__ gcursor) {
    int e = blockIdx.x;      // 0..127
    int j = threadIdx.x;     // 0..255
    if (e == 0) gcursor[j] = 0;          // NRANGE == 256 == blockDim
    float acc = 0.f;
    if (j < DD) {
        int c = j;
        #pragma unroll 4
        for (int d = 0; d < DD; ++d)
            acc += Wqkv[c*3*DD + d] * Wqkv[e*3*DD + DD + d];
    } else {
        int o = j - DD;
        #pragma unroll 4
        for (int d = 0; d < DD; ++d)
            acc += Wqkv[e*3*DD + 2*DD + d] * Wout[d*DD + o];
    }
    Bmat[e*2*DD + j] = acc;
}

// ---------------------------------------------------------------------------
// Phase A: radix partition (each edge scanned once across the grid).
// ---------------------------------------------------------------------------
__global__ __launch_bounds__(256) void partition_kernel(
        const int* __restrict__ idx,
        int* __restrict__ staging,
        int* __restrict__ gcursor) {
    __shared__ int bucket[RPB][BCAP];
    __shared__ int bcnt[RPB];
    __shared__ int gbase[RPB];

    int t  = threadIdx.x;
    int bb = blockIdx.x;
    int batch = bb >> 8;                 // 256 chunks per batch
    int c = bb & 255;
    if (t < RPB) bcnt[t] = 0;
    __syncthreads();

    int4 v = reinterpret_cast<const int4*>(idx)[batch*(NK/4) + c*256 + t];
    int nrow = (c*256 + t) >> 3;         // 8 int4 (32 edges) per source row
    int mm[4] = {v.x, v.y, v.z, v.w};
    #pragma unroll
    for (int j = 0; j < 4; ++j) {
        int m = mm[j];
        int r = m >> 7;
        int p = atomicAdd(&bcnt[r], 1);
        if (p < BCAP) bucket[r][p] = ((m & 127) << 13) | nrow;
    }
    __syncthreads();

    if (t < RPB) {
        int n = min(bcnt[t], BCAP);
        bcnt[t] = n;
        gbase[t] = atomicAdd(&gcursor[batch*RPB + t], n);
    }
    __syncthreads();

    for (int u = t; u < RPB*BCAP; u += 256) {
        int k = u / BCAP, s = u % BCAP;
        if (s < bcnt[k])
            staging[(size_t)(batch*RPB + k)*SCAP + gbase[k] + s] = bucket[k][s];
    }
}

// ---------------------------------------------------------------------------
// Phase B: per-range binning -> srcs16 + offsets/counts.
// ---------------------------------------------------------------------------
__global__ __launch_bounds__(512) void bin_kernel(
        const int* __restrict__ staging,
        const int* __restrict__ gcursor,
        unsigned short* __restrict__ srcs16,
        int* __restrict__ offsets,
        int* __restrict__ counts) {
    __shared__ unsigned short binned[RCAP];
    __shared__ int hist[RROWS], pfx[RROWS], cur[RROWS];

    int t  = threadIdx.x;
    int rg = blockIdx.x;                 // batch*64 + r
    int cnt = gcursor[rg];
    if (cnt > SCAP) cnt = SCAP;
    const int* sp = staging + (size_t)rg*SCAP;

    if (t < RROWS) { hist[t] = 0; cur[t] = 0; }
    __syncthreads();

    for (int u = t; u < cnt; u += 512)
        atomicAdd(&hist[sp[u] >> 13], 1);
    __syncthreads();

    if (t < 64) {
        int a = hist[2*t], b = hist[2*t+1];
        int s = a + b;
        #pragma unroll
        for (int d = 1; d < 64; d <<= 1) {
            int v = __shfl_up(s, d, 64);
            if (t >= d) s += v;
        }
        int excl = s - (a + b);
        pfx[2*t]   = excl;
        pfx[2*t+1] = excl + a;
    }
    __syncthreads();

    for (int u = t; u < cnt; u += 512) {
        int e = sp[u];
        int ml = e >> 13;
        int p = atomicAdd(&cur[ml], 1);
        binned[pfx[ml] + p] = (unsigned short)(e & 8191);
    }
    __syncthreads();

    int base = rg * RCAP;
    for (int u = t; u < cnt; u += 512) srcs16[base + u] = binned[u];
    if (t < RROWS) {
        int grow = (rg >> 6)*NN + (rg & 63)*RROWS + t;
        offsets[grow] = base + pfx[t];
        counts[grow]  = hist[t];
    }
}

// ---------------------------------------------------------------------------
// One diffusion hop, gather form, column-split; 8 static gather slots/lane.
// ---------------------------------------------------------------------------
__global__ __launch_bounds__(256) void hop_kernel(
        const float* __restrict__ fin, float* __restrict__ fout,
        const int* __restrict__ offsets, const int* __restrict__ counts,
        const unsigned short* __restrict__ srcs16) {
    int i = blockIdx.x;                 // 0..16383
    int xcd = i & 7;
    int batch = xcd >> 1, ch = xcd & 1;
    int j = i >> 3;                     // 0..2047
    int wave = threadIdx.x >> 6;
    int lane = threadIdx.x & 63;
    int h = lane >> 4;                  // stream 0..3
    int l16 = lane & 15;
    int g = batch*NN + j*4 + wave;      // global dest row

    int off = offsets[g];
    int cnt = counts[g];
    const unsigned short* sp = srcs16 + off;
    const float* fbatch = fin + (size_t)batch*NN*DD;
    int laneoff = ch*64 + l16*4;

    int ss[8];
    #pragma unroll
    for (int u = 0; u < 8; ++u) {
        int s = sp[h + 4*u];
        ss[u] = (s > NN-1) ? 0 : s;
    }
    float4 vv[8];
    #pragma unroll
    for (int u = 0; u < 8; ++u)
        vv[u] = *reinterpret_cast<const float4*>(fbatch + ss[u]*DD + laneoff);
    float4 acc = make_float4(0.f, 0.f, 0.f, 0.f);
    #pragma unroll
    for (int u = 0; u < 8; ++u) {
        float mwt = (h + 4*u < cnt) ? 1.f : 0.f;
        acc.x += vv[u].x * mwt; acc.y += vv[u].y * mwt;
        acc.z += vv[u].z * mwt; acc.w += vv[u].w * mwt;
    }
    for (int e = 32 + h; e < cnt; e += 4) {
        int s = sp[e];
        float4 v = *reinterpret_cast<const float4*>(fbatch + s*DD + laneoff);
        acc.x += v.x; acc.y += v.y; acc.z += v.z; acc.w += v.w;
    }

    acc.x += __shfl_xor(acc.x, 16); acc.y += __shfl_xor(acc.y, 16);
    acc.z += __shfl_xor(acc.z, 16); acc.w += __shfl_xor(acc.w, 16);
    acc.x += __shfl_xor(acc.x, 32); acc.y += __shfl_xor(acc.y, 32);
    acc.z += __shfl_xor(acc.z, 32); acc.w += __shfl_xor(acc.w, 32);

    if (h == 0) {
        const float s = inv_denom();
        float4 o = make_float4(acc.x*s, acc.y*s, acc.z*s, acc.w*s);
        *reinterpret_cast<float4*>(fout + (size_t)g*DD + laneoff) = o;
    }
}

// ---------------------------------------------------------------------------
// Fused final stage, 64-row tiles (8x8 acc = best FMA:load ratio) with
// EXPLICIT register double-buffer prefetch of Bmat k-chunks: the next
// 4-k chunk's 8 float4 loads are issued before the current chunk's 512
// FMAs, alternating buffers (no register moves). ILP covers the L2
// latency that 2 waves/SIMD of TLP cannot.
// ---------------------------------------------------------------------------
__global__ __launch_bounds__(256) void final_kernel(
        const float* __restrict__ x3, const float* __restrict__ x,
        const float* __restrict__ Bmat, const float* __restrict__ bout,
        float* __restrict__ out) {
    __shared__ float a_lds[64][DD];
    __shared__ float attn_lds[64];
    int t = threadIdx.x;
    int tc = t & 31, tr = t >> 5;       // tc: 8 cols each; tr: 8 rows each
    int row0 = blockIdx.x * 64;

    for (int u = t; u < 64*32; u += 256) {
        int r = u >> 5, cp = u & 31;
        *reinterpret_cast<float4*>(&a_lds[r][cp*4]) =
            *reinterpret_cast<const float4*>(x3 + (size_t)(row0 + r)*DD + cp*4);
    }
    if (t < 64) attn_lds[t] = 0.f;

    const float* bp = Bmat + tc*8;      // this thread's column slice
    float4 pa0[4], pa1[4], pb0[4], pb1[4];
    #pragma unroll
    for (int kk = 0; kk < 4; ++kk) {
        pa0[kk] = *reinterpret_cast<const float4*>(bp + kk*256);
        pa1[kk] = *reinterpret_cast<const float4*>(bp + kk*256 + 4);
    }
    __syncthreads();

    float acc[8][8];
    #pragma unroll
    for (int r = 0; r < 8; ++r)
        #pragma unroll
        for (int u = 0; u < 8; ++u) acc[r][u] = 0.f;

    #pragma unroll 1
    for (int k0 = 0; k0 < DD; k0 += 8) {
        // prefetch chunk k0+4 into B while computing on A
        int kn = (k0 + 4 < DD) ? (k0 + 4) : 0;
        #pragma unroll
        for (int kk = 0; kk < 4; ++kk) {
            pb0[kk] = *reinterpret_cast<const float4*>(bp + (kn+kk)*256);
            pb1[kk] = *reinterpret_cast<const float4*>(bp + (kn+kk)*256 + 4);
        }
        {
            float4 av[8];
            #pragma unroll
            for (int r = 0; r < 8; ++r)
                av[r] = *reinterpret_cast<const float4*>(&a_lds[tr*8 + r][k0]);
            #pragma unroll
            for (int kk = 0; kk < 4; ++kk) {
                #pragma unroll
                for (int r = 0; r < 8; ++r) {
                    float a = (kk == 0) ? av[r].x : (kk == 1) ? av[r].y
                            : (kk == 2) ? av[r].z : av[r].w;
                    acc[r][0] += a*pa0[kk].x; acc[r][1] += a*pa0[kk].y;
                    acc[r][2] += a*pa0[kk].z; acc[r][3] += a*pa0[kk].w;
                    acc[r][4] += a*pa1[kk].x; acc[r][5] += a*pa1[kk].y;
                    acc[r][6] += a*pa1[kk].z; acc[r][7] += a*pa1[kk].w;
                }
            }
        }
        // prefetch chunk k0+8 into A while computing on B
        int km = (k0 + 8 < DD) ? (k0 + 8) : 0;
        #pragma unroll
        for (int kk = 0; kk < 4; ++kk) {
            pa0[kk] = *reinterpret_cast<const float4*>(bp + (km+kk)*256);
            pa1[kk] = *reinterpret_cast<const float4*>(bp + (km+kk)*256 + 4);
        }
        {
            float4 av[8];
            #pragma unroll
            for (int r = 0; r < 8; ++r)
                av[r] = *reinterpret_cast<const float4*>(&a_lds[tr*8 + r][k0 + 4]);
            #pragma unroll
            for (int kk = 0; kk < 4; ++kk) {
                #pragma unroll
                for (int r = 0; r < 8; ++r) {
                    float a = (kk == 0) ? av[r].x : (kk == 1) ? av[r].y
                            : (kk == 2) ? av[r].z : av[r].w;
                    acc[r][0] += a*pb0[kk].x; acc[r][1] += a*pb0[kk].y;
                    acc[r][2] += a*pb0[kk].z; acc[r][3] += a*pb0[kk].w;
                    acc[r][4] += a*pb1[kk].x; acc[r][5] += a*pb1[kk].y;
                    acc[r][6] += a*pb1[kk].z; acc[r][7] += a*pb1[kk].w;
                }
            }
        }
    }

    if (tc < 16) {
        #pragma unroll
        for (int r = 0; r < 8; ++r) {
            int row = row0 + tr*8 + r;
            const float4 xa = *reinterpret_cast<const float4*>(x + (size_t)row*DD + tc*8);
            const float4 xb = *reinterpret_cast<const float4*>(x + (size_t)row*DD + tc*8 + 4);
            float p = xa.x*acc[r][0] + xa.y*acc[r][1] + xa.z*acc[r][2] + xa.w*acc[r][3]
                    + xb.x*acc[r][4] + xb.y*acc[r][5] + xb.z*acc[r][6] + xb.w*acc[r][7];
            atomicAdd(&attn_lds[tr*8 + r], p);
        }
    }
    __syncthreads();

    if (tc >= 16) {
        int c0 = (tc - 16) * 8;
        float4 ba  = *reinterpret_cast<const float4*>(bout + c0);
        float4 bbv = *reinterpret_cast<const float4*>(bout + c0 + 4);
        #pragma unroll
        for (int r = 0; r < 8; ++r) {
            int row = row0 + tr*8 + r;
            float at = attn_lds[tr*8 + r];
            float4 o0, o1;
            o0.x = at*acc[r][0] + ba.x;  o0.y = at*acc[r][1] + ba.y;
            o0.z = at*acc[r][2] + ba.z;  o0.w = at*acc[r][3] + ba.w;
            o1.x = at*acc[r][4] + bbv.x; o1.y = at*acc[r][5] + bbv.y;
            o1.z = at*acc[r][6] + bbv.z; o1.w = at*acc[r][7] + bbv.w;
            *reinterpret_cast<float4*>(out + (size_t)row*DD + c0)     = o0;
            *reinterpret_cast<float4*>(out + (size_t)row*DD + c0 + 4) = o1;
        }
    }
}

// ---------------------------------------------------------------------------
// ws layout (~24.3 MB; measured ws_size ~268 MB):
//   f_a     @ 0         16777216 B   (x3 ping buffer)
//   srcs16  @ 16777216   2359552 B   (256*4608 u16 + pad)
//   offsets @ 19136768    131072 B
//   counts  @ 19267840    131072 B
//   Bmat    @ 19398912    131072 B
//   staging @ 19529984   4718592 B   (256*4608 int)
//   gcursor @ 24248576      1024 B
// ---------------------------------------------------------------------------
extern "C" void kernel_launch(void* const* d_in, const int* in_sizes, int n_in,
                              void* d_out, int out_size, void* d_ws, size_t ws_size,
                              hipStream_t stream) {
    const float* x    = (const float*)d_in[0];
    const int*   idx  = (const int*)  d_in[1];
    const float* Wqkv = (const float*)d_in[2];
    const float* Wout = (const float*)d_in[3];
    const float* bout = (const float*)d_in[4];
    float* out = (float*)d_out;

    char* ws = (char*)d_ws;
    float*          f_a     = (float*)(ws);
    unsigned short* srcs16  = (unsigned short*)(ws + 16777216);
    int*            offsets = (int*)(ws + 19136768);
    int*            counts  = (int*)(ws + 19267840);
    float*          Bmat    = (float*)(ws + 19398912);
    int*            staging = (int*)(ws + 19529984);
    int*            gcursor = (int*)(ws + 24248576);

    compute_bmat<<<DD, 256, 0, stream>>>(Wqkv, Wout, Bmat, gcursor);
    partition_kernel<<<1024, 256, 0, stream>>>(idx, staging, gcursor);
    bin_kernel<<<NRANGE, 512, 0, stream>>>(staging, gcursor, srcs16, offsets, counts);

    hop_kernel<<<16384, 256, 0, stream>>>(x,   f_a, offsets, counts, srcs16);
    hop_kernel<<<16384, 256, 0, stream>>>(f_a, out, offsets, counts, srcs16);
    hop_kernel<<<16384, 256, 0, stream>>>(out, f_a, offsets, counts, srcs16);

    final_kernel<<<BN/64, 256, 0, stream>>>(f_a, x, Bmat, bout, out);
}